// Round 10
// baseline (20.384 us; speedup 1.0000x reference)
//
#include <hip/hip_runtime.h>
#include <hip/hip_bf16.h>

// FrameReducer: N=16, T=2048, C=512, V=500 — two dispatches, full-chip stage 1.
//
// Kernel 1 (mask_emit): grid (B=T/128, N) x 128 thr = 256 blocks (full chip),
//   ONE strided ctc load per thread. Per block: 2-wave ballot, wave1 offset via
//   LDS handoff, stable local compaction into seg[n][b*128 + local] = t;
//   cnt[n][b] = segment count. No cross-block coordination (R4 lesson: no
//   grid.sync; R9 lesson: 16-block compact was the remaining latency slack).
// Kernel 2 (gather): grid (ceil(Tp*128/256), N), 256 thr, one 16B vec/thread.
//   Per block: thread-0 scans cnt[n][0..B) (one 64B line, L1-resident) into
//   LDS pfx; p is wave-uniform -> scalar 4-step binary search -> seg lookup
//   (scalar broadcast) -> NT load x row chunk, NT store out. p >= lens rows
//   write zeros every call (harness poisons d_out once, never re-poisons).
//   Block (0,n) writes the float lens tail of d_out.

typedef float f32x4 __attribute__((ext_vector_type(4)));

__global__ __launch_bounds__(128) void mask_emit_kernel(
        const float* __restrict__ ctc,
        const void* __restrict__ x_lens_raw,
        const int* __restrict__ blank_id_p,
        int N, int T, int V,
        int* __restrict__ seg,
        int* __restrict__ cnt) {
    const int n    = blockIdx.y;
    const int b    = blockIdx.x;          // segment id, 128 t's each
    const int tid  = threadIdx.x;         // 128 = 2 waves
    const int lane = tid & 63;
    const int w    = tid >> 6;
    const int B    = gridDim.x;
    const int t    = b * 128 + tid;

    // x_lens dtype detection: values in [1,T], never 0 -> int64 layout iff
    // int32 view at odd index is 0.
    const int* li = (const int*)x_lens_raw;
    long long L = (N > 1 && li[1] == 0) ? ((const long long*)x_lens_raw)[n]
                                        : (long long)li[n];

    bool keep = false;
    if (t < T) {
        float v = ctc[((long long)n * T + t) * V + *blank_id_p];
        keep = (v < -0.10536052f) && ((long long)t < L);   // float32(log(0.9))
    }
    unsigned long long bal = __ballot(keep);

    __shared__ int w0cnt;
    if (w == 0 && lane == 0) w0cnt = __popcll(bal);
    __syncthreads();

    const int base = (w == 0) ? 0 : w0cnt;
    if (keep) {
        int rank = __popcll(bal & ((1ull << lane) - 1ull));
        seg[n * T + b * 128 + base + rank] = t;
    }
    if (w == 1 && lane == 0) cnt[n * B + b] = w0cnt + __popcll(bal);
}

__global__ __launch_bounds__(256) void gather_kernel(
        const f32x4* __restrict__ x,
        const int* __restrict__ seg,
        const int* __restrict__ cnt,
        f32x4* __restrict__ out,
        float* __restrict__ lens_out,
        int Tp, int T, int B, int f4_per_seq) {
    const int n = blockIdx.y;
    __shared__ int pfx[33];               // B <= 32

    if (threadIdx.x == 0) {
        int acc = 0;
        const int* c = cnt + n * B;
        for (int i = 0; i < B; ++i) { pfx[i] = acc; acc += c[i]; }
        pfx[B] = acc;
    }
    __syncthreads();
    const int lens = pfx[B];
    if (blockIdx.x == 0 && threadIdx.x == 0) lens_out[n] = (float)lens;

    const int gid = blockIdx.x * 256 + threadIdx.x;   // f4 index within sequence
    if (gid >= f4_per_seq) return;
    const int p  = gid >> 7;                          // wave-uniform (128 f4/row)
    const int c4 = gid & 127;

    f32x4 v = (f32x4)0.f;
    if (p < lens) {
        int lo = 0, hi = B;                           // largest i: pfx[i] <= p
        while (hi - lo > 1) {
            int mid = (lo + hi) >> 1;
            if (pfx[mid] <= p) lo = mid; else hi = mid;
        }
        int tsrc = seg[n * T + lo * 128 + (p - pfx[lo])];   // scalar broadcast
        v = __builtin_nontemporal_load(x + ((long long)(n * T + tsrc) << 7) + c4);
    }
    __builtin_nontemporal_store(v, out + ((long long)n * Tp << 7) + gid);
}

extern "C" void kernel_launch(void* const* d_in, const int* in_sizes, int n_in,
                              void* d_out, int out_size, void* d_ws, size_t ws_size,
                              hipStream_t stream) {
    const float* x        = (const float*)d_in[0];
    const void*  x_lens   = d_in[1];
    const float* ctc      = (const float*)d_in[2];
    const int*   blank_id = (const int*)d_in[3];

    const int N = in_sizes[1];               // 16
    const int C = 512;
    const int V = 500;
    const int T = in_sizes[0] / (N * C);     // 2048
    const int Tp = (out_size - N) / (N * C); // T'
    const int B = (T + 127) / 128;           // 16 segments per sequence

    int* seg = (int*)d_ws;                   // [N][T] (segment-local compaction)
    int* cnt = seg + (long long)N * T;       // [N][B]

    float* out      = (float*)d_out;                   // [N][Tp][C]
    float* lens_out = out + (long long)N * Tp * C;     // [N] float

    dim3 mgrid(B, N);
    mask_emit_kernel<<<mgrid, 128, 0, stream>>>(ctc, x_lens, blank_id,
                                                N, T, V, seg, cnt);

    const int f4_per_seq = Tp * (C / 4);     // Tp*128
    dim3 ggrid((f4_per_seq + 255) / 256, N);
    gather_kernel<<<ggrid, 256, 0, stream>>>((const f32x4*)x, seg, cnt,
                                             (f32x4*)out, lens_out,
                                             Tp, T, B, f4_per_seq);
}

// Round 11
// 17.802 us; speedup vs baseline: 1.1450x; 1.1450x over previous
//
#include <hip/hip_runtime.h>
#include <hip/hip_bf16.h>

// FrameReducer: N=16, T=2048, C=512, V=500 — two dispatches.
//
// Kernel 1 (mask_emit): grid (B=T/128, N) x 128 thr = 256 blocks (full chip),
//   ONE strided ctc load per thread. Stable segment-local compaction:
//   seg[n][b*128 + local] = t, cnt[n][b] = count. (R9's 16-block compact was
//   ~2.5us latency-bound on 16 CUs; this spreads it across the chip.)
// Kernel 2 (gather): grid (ceil(Tp*128/256), N), 256 thr, one 16B vec/thread.
//   Per block: wave shfl scan of cnt[n][0..B) -> LDS pfx (NO serial thread-0
//   loop — that was R10's regression, R2 redux). p wave-uniform -> 4-step
//   binary search -> seg lookup (scalar broadcast) -> REGULAR x load (L3-
//   resident; R10's NT loads forced HBM re-fetch) -> NT store (R9's win:
//   out is write-once, skip cache allocation). Zero tail rows written every
//   call (harness poisons d_out once, never re-poisons). Block (0,n) writes
//   the float lens tail.

typedef float f32x4 __attribute__((ext_vector_type(4)));

__global__ __launch_bounds__(128) void mask_emit_kernel(
        const float* __restrict__ ctc,
        const void* __restrict__ x_lens_raw,
        const int* __restrict__ blank_id_p,
        int N, int T, int V,
        int* __restrict__ seg,
        int* __restrict__ cnt) {
    const int n    = blockIdx.y;
    const int b    = blockIdx.x;          // segment id, 128 t's each
    const int tid  = threadIdx.x;         // 128 = 2 waves
    const int lane = tid & 63;
    const int w    = tid >> 6;
    const int B    = gridDim.x;
    const int t    = b * 128 + tid;

    // x_lens dtype detection: values in [1,T], never 0 -> int64 layout iff
    // int32 view at odd index is 0.
    const int* li = (const int*)x_lens_raw;
    long long L = (N > 1 && li[1] == 0) ? ((const long long*)x_lens_raw)[n]
                                        : (long long)li[n];

    bool keep = false;
    if (t < T) {
        float v = ctc[((long long)n * T + t) * V + *blank_id_p];
        keep = (v < -0.10536052f) && ((long long)t < L);   // float32(log(0.9))
    }
    unsigned long long bal = __ballot(keep);

    __shared__ int w0cnt;
    if (w == 0 && lane == 0) w0cnt = __popcll(bal);
    __syncthreads();

    const int base = (w == 0) ? 0 : w0cnt;
    if (keep) {
        int rank = __popcll(bal & ((1ull << lane) - 1ull));
        seg[n * T + b * 128 + base + rank] = t;
    }
    if (w == 1 && lane == 0) cnt[n * B + b] = w0cnt + __popcll(bal);
}

__global__ __launch_bounds__(256) void gather_kernel(
        const f32x4* __restrict__ x,
        const int* __restrict__ seg,
        const int* __restrict__ cnt,
        f32x4* __restrict__ out,
        float* __restrict__ lens_out,
        int Tp, int T, int B, int f4_per_seq) {
    const int n   = blockIdx.y;
    const int tid = threadIdx.x;
    const int lane = tid & 63;
    __shared__ int pfx[33];               // B <= 32; pfx[B] = lens

    if (tid < 64) {                       // wave shfl scan, no serial loop
        int incl = (tid < B) ? cnt[n * B + tid] : 0;
        #pragma unroll
        for (int d = 1; d < 64; d <<= 1) {
            int o = __shfl_up(incl, d, 64);
            if (lane >= d) incl += o;
        }
        if (tid < B) pfx[tid + 1] = incl;
        if (tid == 0) pfx[0] = 0;
    }
    __syncthreads();
    const int lens = pfx[B];
    if (blockIdx.x == 0 && tid == 0) lens_out[n] = (float)lens;

    const int gid = blockIdx.x * 256 + tid;   // f4 index within sequence
    if (gid >= f4_per_seq) return;
    const int p  = gid >> 7;                  // wave-uniform (128 f4/row)
    const int c4 = gid & 127;

    f32x4 v = (f32x4)0.f;
    if (p < lens) {
        int lo = 0, hi = B;                   // largest i: pfx[i] <= p
        while (hi - lo > 1) {
            int mid = (lo + hi) >> 1;
            if (pfx[mid] <= p) lo = mid; else hi = mid;
        }
        int tsrc = seg[n * T + lo * 128 + (p - pfx[lo])];   // scalar broadcast
        v = x[((long long)(n * T + tsrc) << 7) + c4];       // regular load (L3)
    }
    __builtin_nontemporal_store(v, out + ((long long)n * Tp << 7) + gid);
}

extern "C" void kernel_launch(void* const* d_in, const int* in_sizes, int n_in,
                              void* d_out, int out_size, void* d_ws, size_t ws_size,
                              hipStream_t stream) {
    const float* x        = (const float*)d_in[0];
    const void*  x_lens   = d_in[1];
    const float* ctc      = (const float*)d_in[2];
    const int*   blank_id = (const int*)d_in[3];

    const int N = in_sizes[1];               // 16
    const int C = 512;
    const int V = 500;
    const int T = in_sizes[0] / (N * C);     // 2048
    const int Tp = (out_size - N) / (N * C); // T'
    const int B = (T + 127) / 128;           // 16 segments per sequence

    int* seg = (int*)d_ws;                   // [N][T] (segment-local compaction)
    int* cnt = seg + (long long)N * T;       // [N][B]

    float* out      = (float*)d_out;                   // [N][Tp][C]
    float* lens_out = out + (long long)N * Tp * C;     // [N] float

    dim3 mgrid(B, N);
    mask_emit_kernel<<<mgrid, 128, 0, stream>>>(ctc, x_lens, blank_id,
                                                N, T, V, seg, cnt);

    const int f4_per_seq = Tp * (C / 4);     // Tp*128
    dim3 ggrid((f4_per_seq + 255) / 256, N);
    gather_kernel<<<ggrid, 256, 0, stream>>>((const f32x4*)x, seg, cnt,
                                             (f32x4*)out, lens_out,
                                             Tp, T, B, f4_per_seq);
}